// Round 1
// baseline (440.500 us; speedup 1.0000x reference)
//
#include <hip/hip_runtime.h>
#include <hip/hip_bf16.h>
#include <cstdint>
#include <cstddef>

#define M_DIM 8192
#define K_DIM 4096
#define N_DIM 4096

typedef __bf16 bf16x8 __attribute__((ext_vector_type(8)));
typedef float  f32x4  __attribute__((ext_vector_type(4)));

__device__ __forceinline__ unsigned short f32_to_bf16_rne(float f) {
  unsigned int u = __builtin_bit_cast(unsigned int, f);
  u += 0x7FFFu + ((u >> 16) & 1u);
  return (unsigned short)(u >> 16);
}

// fp32 -> bf16 conversion, vectorized (float4 in, ushort4 out), grid-stride.
__global__ void __launch_bounds__(256) cvt_f32_bf16(const float* __restrict__ src,
                                                    unsigned short* __restrict__ dst,
                                                    int n4) {
  int i = blockIdx.x * blockDim.x + threadIdx.x;
  int stride = gridDim.x * blockDim.x;
  for (; i < n4; i += stride) {
    float4 v = reinterpret_cast<const float4*>(src)[i];
    ushort4 o;
    o.x = f32_to_bf16_rne(v.x);
    o.y = f32_to_bf16_rne(v.y);
    o.z = f32_to_bf16_rne(v.z);
    o.w = f32_to_bf16_rne(v.w);
    reinterpret_cast<ushort4*>(dst)[i] = o;
  }
}

__device__ __forceinline__ void gload_lds16(const void* g, void* lds) {
  __builtin_amdgcn_global_load_lds((const __attribute__((address_space(1))) void*)g,
                                   (__attribute__((address_space(3))) void*)lds,
                                   16, 0, 0);
}

// m97-structure 128x128 tile GEMM, B^T layout (W is [OUT][IN] row-major).
// 4 waves (2x2), each owns a 64x64 quadrant = 4x4 fragments of 16x16.
// BK=32, single-buffered LDS, global_load_lds width-16 staging.
__global__ void __launch_bounds__(256) gemm_bt_bias(const __bf16* __restrict__ A,
                                                    const __bf16* __restrict__ W,
                                                    const float* __restrict__ bias,
                                                    float* __restrict__ out) {
  __shared__ __align__(16) __bf16 Als[128 * 32];
  __shared__ __align__(16) __bf16 Bls[128 * 32];

  const int tid  = threadIdx.x;
  const int wave = tid >> 6;
  const int lane = tid & 63;

  // XCD-aware bijective swizzle (2048 % 8 == 0): each XCD gets a contiguous
  // chunk of 256 original ids = 4 full B-panels -> L2 locality.
  const int bid = (blockIdx.x & 7) * 256 + (blockIdx.x >> 3);
  const int bm = bid & 63;   // 64 M-tiles (fast dim: consecutive ids share B-panel)
  const int bn = bid >> 6;   // 32 N-tiles
  const int brow = bm * 128;
  const int bcol = bn * 128;

  // Staging: LDS tile is [128 rows][32 k] bf16, linear. Each of 4 waves stages
  // 2 KiB of A and 2 KiB of B per K-step via 2+2 global_load_lds_dwordx4.
  // lane l covers row (l>>2), 16-byte k-group (l&3) within a 16-row chunk.
  const int srow = wave * 32 + (lane >> 2);
  const int scol = (lane & 3) * 8;  // bf16 elements
  const __bf16* ga0 = A + (size_t)(brow + srow) * K_DIM + scol;
  const __bf16* ga1 = A + (size_t)(brow + srow + 16) * K_DIM + scol;
  const __bf16* gb0 = W + (size_t)(bcol + srow) * K_DIM + scol;
  const __bf16* gb1 = W + (size_t)(bcol + srow + 16) * K_DIM + scol;
  __bf16* lA0 = &Als[(wave * 32) * 32];        // wave-uniform LDS bases
  __bf16* lA1 = &Als[(wave * 32 + 16) * 32];
  __bf16* lB0 = &Bls[(wave * 32) * 32];
  __bf16* lB1 = &Bls[(wave * 32 + 16) * 32];

  const int wr = wave >> 1;        // wave row (0..1), 64-row quadrant
  const int wc = wave & 1;         // wave col (0..1), 64-col quadrant
  const int fr = lane & 15;        // fragment row/col index
  const int fk = (lane >> 4) * 8;  // fragment k-group (8 bf16)

  f32x4 acc[4][4] = {};

  for (int kt = 0; kt < K_DIM; kt += 32) {
    gload_lds16(ga0 + kt, lA0);
    gload_lds16(ga1 + kt, lA1);
    gload_lds16(gb0 + kt, lB0);
    gload_lds16(gb1 + kt, lB1);
    __syncthreads();  // drains vmcnt(0): staged tile visible

    bf16x8 af[4], bfr[4];
#pragma unroll
    for (int i = 0; i < 4; ++i)
      af[i] = *(const bf16x8*)&Als[(wr * 64 + i * 16 + fr) * 32 + fk];
#pragma unroll
    for (int i = 0; i < 4; ++i)
      bfr[i] = *(const bf16x8*)&Bls[(wc * 64 + i * 16 + fr) * 32 + fk];

#pragma unroll
    for (int mi = 0; mi < 4; ++mi)
#pragma unroll
      for (int ni = 0; ni < 4; ++ni)
        acc[mi][ni] = __builtin_amdgcn_mfma_f32_16x16x32_bf16(
            af[mi], bfr[ni], acc[mi][ni], 0, 0, 0);

    __syncthreads();  // all waves done reading before next stage overwrites
  }

  // Epilogue: C/D mapping col=lane&15, row=(lane>>4)*4+j (m89-verified).
  const int orow = brow + wr * 64 + (lane >> 4) * 4;
  const int ocol = bcol + wc * 64 + fr;
#pragma unroll
  for (int ni = 0; ni < 4; ++ni) {
    float bv = bias[ocol + ni * 16];
#pragma unroll
    for (int mi = 0; mi < 4; ++mi)
#pragma unroll
      for (int j = 0; j < 4; ++j)
        out[(size_t)(orow + mi * 16 + j) * N_DIM + (ocol + ni * 16)] =
            acc[mi][ni][j] + bv;
  }
}

// Safety net if d_ws is too small for bf16 copies of A and W: correct but slow.
__global__ void naive_linear(const float* __restrict__ A, const float* __restrict__ W,
                             const float* __restrict__ bias, float* __restrict__ out) {
  int n = blockIdx.y;
  int o = blockIdx.x * 256 + threadIdx.x;
  const float* a = A + (size_t)n * K_DIM;
  const float* w = W + (size_t)o * K_DIM;
  float acc = 0.f;
  for (int k = 0; k < K_DIM; ++k) acc += a[k] * w[k];
  out[(size_t)n * N_DIM + o] = acc + bias[o];
}

extern "C" void kernel_launch(void* const* d_in, const int* in_sizes, int n_in,
                              void* d_out, int out_size, void* d_ws, size_t ws_size,
                              hipStream_t stream) {
  const float* A    = (const float*)d_in[0];
  const float* W    = (const float*)d_in[1];
  const float* bias = (const float*)d_in[2];
  float* out = (float*)d_out;

  const size_t a_elems = (size_t)M_DIM * K_DIM;  // 33.5M
  const size_t w_elems = (size_t)N_DIM * K_DIM;  // 16.8M
  const size_t need = (a_elems + w_elems) * sizeof(unsigned short);  // 96 MiB

  if (ws_size < need) {
    naive_linear<<<dim3(N_DIM / 256, M_DIM), 256, 0, stream>>>(A, W, bias, out);
    return;
  }

  unsigned short* Abf = (unsigned short*)d_ws;
  unsigned short* Wbf = Abf + a_elems;
  cvt_f32_bf16<<<2048, 256, 0, stream>>>(A, Abf, (int)(a_elems / 4));
  cvt_f32_bf16<<<2048, 256, 0, stream>>>(W, Wbf, (int)(w_elems / 4));
  gemm_bt_bias<<<2048, 256, 0, stream>>>((const __bf16*)Abf, (const __bf16*)Wbf,
                                         bias, out);
}

// Round 3
// 282.026 us; speedup vs baseline: 1.5619x; 1.5619x over previous
//
#include <hip/hip_runtime.h>
#include <hip/hip_bf16.h>
#include <cstdint>
#include <cstddef>

#define M_DIM 8192
#define K_DIM 4096
#define N_DIM 4096

typedef __bf16 bf16x8 __attribute__((ext_vector_type(8)));
typedef float  f32x4  __attribute__((ext_vector_type(4)));

__device__ __forceinline__ unsigned short f32_to_bf16_rne(float f) {
  unsigned int u = __builtin_bit_cast(unsigned int, f);
  u += 0x7FFFu + ((u >> 16) & 1u);
  return (unsigned short)(u >> 16);
}

__global__ void __launch_bounds__(256) cvt_f32_bf16(const float* __restrict__ src,
                                                    unsigned short* __restrict__ dst,
                                                    int n4) {
  int i = blockIdx.x * blockDim.x + threadIdx.x;
  int stride = gridDim.x * blockDim.x;
  for (; i < n4; i += stride) {
    float4 v = reinterpret_cast<const float4*>(src)[i];
    ushort4 o;
    o.x = f32_to_bf16_rne(v.x);
    o.y = f32_to_bf16_rne(v.y);
    o.z = f32_to_bf16_rne(v.z);
    o.w = f32_to_bf16_rne(v.w);
    reinterpret_cast<ushort4*>(dst)[i] = o;
  }
}

__device__ __forceinline__ void gload16(const void* g, void* l) {
  __builtin_amdgcn_global_load_lds((const __attribute__((address_space(1))) void*)g,
                                   (__attribute__((address_space(3))) void*)l, 16, 0, 0);
}

// 256x256-tile, BK=64, 8-wave (2Mx4N), 8-phase pipelined GEMM (m201 template).
// LDS: 2 buffers x (A[256][64] + B[256][64]) bf16 = 128 KiB, rows linear at
// 128 B stride; 16B-chunk (row, j) holds global k-chunk j ^ (row&7) (T2 swizzle
// via pre-swizzled global source + linear LDS dest + XOR on ds_read — rule 21).
//
// COLLECTIVE read/stage audit (the round-2 bug was auditing per-wave, not
// collectively). With wm in {0,1}, wn in {0..3}:
//   LDA8(b,mh) collectively reads A rows {mh*64..+63} u {128+mh*64..+63}
//     -> touches BOTH A halves. A fully read after ph1 (mh=0) + ph3 (mh=1).
//   LDB4(b,nh) collectively reads B rows wn*64+nh*32..+31 over wn
//     -> touches BOTH B halves. B fully read after ph1 (nh=0) + ph2 (nh=1).
// Last collective reads: buf0.B end-ph2, buf0.A end-ph3, buf1.B end-ph6,
// buf1.A end-ph7. Stage slot for region R must be >= 1 phase after R's last
// read (end-of-phase BAR + each reader's own lgkmcnt(0) before that BAR
// guarantee all reads complete before any wave issues the phase-p write):
//   ph1: b1.A0<-k+1 (A last read prev ph7)   ph2: b1.A1<-k+1
//   ph3: b0.B0<-k+2 (B read done end-ph2)    ph4: b0.B1<-k+2
//   ph5: b0.A0<-k+2 (A read done end-ph3)    ph6: b0.A1<-k+2
//   ph7: b1.B0<-k+3 (B read done end-ph6)    ph8: b1.B1<-k+3
// vmcnt gates (2 loads per STAGE, in-order retire, per-wave + BAR):
//   end-ph4: outstanding = {prev ph7,ph8, ph1..ph4} = 12; oldest 8 = all of
//            buf1(k+1) -> VM(4) before ph5 reads.
//   end-ph8: outstanding = {ph3..ph8} = 12; oldest 8 = all of buf0(k+2)
//            -> VM(4) before next ph1 reads. Never vmcnt(0) in steady state.
__global__ void __launch_bounds__(512, 2)
gemm256_8ph(const __bf16* __restrict__ A, const __bf16* __restrict__ W,
            const float* __restrict__ bias, float* __restrict__ out) {
  __shared__ __align__(16) char lds[131072];

  const int tid  = threadIdx.x;
  const int wave = tid >> 6, lane = tid & 63;
  const int wm = wave >> 2, wn = wave & 3;   // 2 x 4 wave grid, each owns 128x64
  const int fr = lane & 15, ko = lane >> 4;

  // Bijective XCD swizzle (512 % 8 == 0): XCD x gets swzid in [x*64,(x+1)*64)
  // = 2 B-panels (4 MB = its L2) shared by 32/32 blocks each.
  const int swzid = ((blockIdx.x & 7) << 6) + (blockIdx.x >> 3);
  const int bm = swzid & 31, bn = swzid >> 5;
  const int brow = bm << 8, bcol = bn << 8;

  // Staging: half-tile = 128 rows x 64 k (16 KiB). 512 threads x 2 gload16.
  // Thread t covers LDS chunks t (rows 0..63) and 512+t (rows 64..127).
  // Global source chunk pre-swizzled: (t&7) ^ (r0&7). LDS dest is the
  // WAVE-UNIFORM base (HW adds lane*16): wave w lanes land at chunk 64w+lane.
  const int r0 = tid >> 3;
  const int jc = (((tid & 7) ^ (r0 & 7)) << 4);
  const char* aSrc = (const char*)A + (size_t)(brow + r0) * (K_DIM * 2) + jc;
  const char* bSrc = (const char*)W + (size_t)(bcol + r0) * (K_DIM * 2) + jc;
  char* dstW = lds + (wave << 10);  // wave-uniform LDS base

#define STAGE(ms, h, bb, kt) do {                                              \
    const char* s_ = ((ms) ? bSrc : aSrc)                                      \
        + (size_t)(h) * (128ull * K_DIM * 2) + (size_t)(kt) * 128;             \
    char* d_ = dstW + (bb) * 65536 + (ms) * 32768 + (h) * 16384;               \
    gload16(s_, d_);                                                           \
    gload16(s_ + 64ull * K_DIM * 2, d_ + 8192);                                \
  } while (0)

  bf16x8 a[4][2];   // current m-half fragments (4 m-frags x 2 k-steps)
  bf16x8 b[4][2];   // 4 n-frags x 2 k-steps (b[0..1]=nh0 live ph1->ph4)
  f32x4 acc[8][4] = {};

#define LDA8(bb, mh) do {                                                      \
    _Pragma("unroll") for (int ml = 0; ml < 4; ++ml)                           \
    _Pragma("unroll") for (int k2 = 0; k2 < 2; ++k2) {                         \
      int ra_ = (wm << 7) + ((mh) << 6) + (ml << 4) + fr;                      \
      int off_ = ((ra_ << 7) + (k2 << 6) + (ko << 4)) ^ ((ra_ & 7) << 4);      \
      a[ml][k2] = *(const bf16x8*)(lds + (bb) * 65536 + off_); }               \
  } while (0)

#define LDB4(bb, nh) do {                                                      \
    _Pragma("unroll") for (int nl = 0; nl < 2; ++nl)                           \
    _Pragma("unroll") for (int k2 = 0; k2 < 2; ++k2) {                         \
      int rb_ = (wn << 6) + ((nh) << 5) + (nl << 4) + fr;                      \
      int off_ = ((rb_ << 7) + (k2 << 6) + (ko << 4)) ^ ((rb_ & 7) << 4);      \
      b[(nh) * 2 + nl][k2] = *(const bf16x8*)(lds + (bb) * 65536 + 32768 + off_); } \
  } while (0)

#define MFMAQ(mh, nh) do {                                                     \
    __builtin_amdgcn_s_setprio(1);                                             \
    _Pragma("unroll") for (int ml = 0; ml < 4; ++ml)                           \
    _Pragma("unroll") for (int nl = 0; nl < 2; ++nl)                           \
    _Pragma("unroll") for (int k2 = 0; k2 < 2; ++k2)                           \
      acc[(mh) * 4 + ml][(nh) * 2 + nl] = __builtin_amdgcn_mfma_f32_16x16x32_bf16( \
          a[ml][k2], b[(nh) * 2 + nl][k2], acc[(mh) * 4 + ml][(nh) * 2 + nl], 0, 0, 0); \
    __builtin_amdgcn_s_setprio(0);                                             \
  } while (0)

#define BAR() __builtin_amdgcn_s_barrier()
#define LGKM0() do { asm volatile("s_waitcnt lgkmcnt(0)" ::: "memory");        \
                     __builtin_amdgcn_sched_barrier(0); } while (0)
#define VM(n) asm volatile("s_waitcnt vmcnt(" #n ")" ::: "memory")

  // Prologue: buf0 <- k0 (all 4 halves), buf1 <- k1 (B0,B1 only; A0,A1 come
  // at iter-0 ph1/ph2). 12 loads outstanding; VM(4) -> oldest 8 = buf0 k0.
  STAGE(1, 0, 0, 0);  // k0.B0
  STAGE(1, 1, 0, 0);  // k0.B1
  STAGE(0, 0, 0, 0);  // k0.A0
  STAGE(0, 1, 0, 0);  // k0.A1
  STAGE(1, 0, 1, 1);  // k1.B0
  STAGE(1, 1, 1, 1);  // k1.B1
  VM(4);
  BAR();

  for (int i = 0; i < 31; ++i) {
    const int kb = 2 * i;
    // ph1: Q(0,0) on buf0 | stage b1.A0 <- k+1
    LDA8(0, 0); LDB4(0, 0); STAGE(0, 0, 1, kb + 1);
    BAR(); LGKM0(); MFMAQ(0, 0); BAR();
    // ph2: Q(0,1) | stage b1.A1 <- k+1
    LDB4(0, 1); STAGE(0, 1, 1, kb + 1);
    BAR(); LGKM0(); MFMAQ(0, 1); BAR();
    // ph3: Q(1,1) | stage b0.B0 <- k+2 (buf0.B reads done end-ph2)
    LDA8(0, 1); STAGE(1, 0, 0, kb + 2);
    BAR(); LGKM0(); MFMAQ(1, 1); BAR();
    // ph4: Q(1,0) | stage b0.B1 <- k+2 | VM(4): buf1(k+1) landed
    STAGE(1, 1, 0, kb + 2);
    BAR(); LGKM0(); MFMAQ(1, 0); VM(4); BAR();
    // ph5: Q(0,0) on buf1 | stage b0.A0 <- k+2 (buf0.A reads done end-ph3)
    LDA8(1, 0); LDB4(1, 0); STAGE(0, 0, 0, kb + 2);
    BAR(); LGKM0(); MFMAQ(0, 0); BAR();
    // ph6: Q(0,1) | stage b0.A1 <- k+2
    LDB4(1, 1); STAGE(0, 1, 0, kb + 2);
    BAR(); LGKM0(); MFMAQ(0, 1); BAR();
    // ph7: Q(1,1) | stage b1.B0 <- k+3 (buf1.B reads done end-ph6)
    LDA8(1, 1); STAGE(1, 0, 1, kb + 3);
    BAR(); LGKM0(); MFMAQ(1, 1); BAR();
    // ph8: Q(1,0) | stage b1.B1 <- k+3 | VM(4): buf0(k+2) landed
    STAGE(1, 1, 1, kb + 3);
    BAR(); LGKM0(); MFMAQ(1, 0); VM(4); BAR();
  }

  // Peel: buf0 = k62, buf1 = k63. Stage only b1.A0/A1 <- k63; VM(0) at ph4
  // (8 outstanding: prev ph7/ph8 B-halves + ph1/ph2 A-halves, all buf1 k63).
  LDA8(0, 0); LDB4(0, 0); STAGE(0, 0, 1, 63);
  BAR(); LGKM0(); MFMAQ(0, 0); BAR();
  LDB4(0, 1); STAGE(0, 1, 1, 63);
  BAR(); LGKM0(); MFMAQ(0, 1); BAR();
  LDA8(0, 1);
  BAR(); LGKM0(); MFMAQ(1, 1); BAR();
  BAR(); LGKM0(); MFMAQ(1, 0); VM(0); BAR();
  LDA8(1, 0); LDB4(1, 0);
  BAR(); LGKM0(); MFMAQ(0, 0); BAR();
  LDB4(1, 1);
  BAR(); LGKM0(); MFMAQ(0, 1); BAR();
  LDA8(1, 1);
  BAR(); LGKM0(); MFMAQ(1, 1); BAR();
  MFMAQ(1, 0);

  // Epilogue: C/D mapping col=lane&15, row=(lane>>4)*4+j (m89-verified), + bias.
  const int oc0 = bcol + (wn << 6) + fr;
  const int or0 = brow + (wm << 7) + (ko << 2);
  float bv[4];
#pragma unroll
  for (int nl = 0; nl < 4; ++nl) bv[nl] = bias[oc0 + nl * 16];
#pragma unroll
  for (int ml = 0; ml < 8; ++ml)
#pragma unroll
    for (int nl = 0; nl < 4; ++nl)
#pragma unroll
      for (int j = 0; j < 4; ++j)
        out[(size_t)(or0 + ml * 16 + j) * N_DIM + (oc0 + nl * 16)] =
            acc[ml][nl][j] + bv[nl];

#undef STAGE
#undef LDA8
#undef LDB4
#undef MFMAQ
#undef BAR
#undef LGKM0
#undef VM
}

// Safety net if d_ws is too small for bf16 copies of A and W: correct but slow.
__global__ void naive_linear(const float* __restrict__ A, const float* __restrict__ W,
                             const float* __restrict__ bias, float* __restrict__ out) {
  int n = blockIdx.y;
  int o = blockIdx.x * 256 + threadIdx.x;
  const float* a = A + (size_t)n * K_DIM;
  const float* w = W + (size_t)o * K_DIM;
  float acc = 0.f;
  for (int k = 0; k < K_DIM; ++k) acc += a[k] * w[k];
  out[(size_t)n * N_DIM + o] = acc + bias[o];
}

extern "C" void kernel_launch(void* const* d_in, const int* in_sizes, int n_in,
                              void* d_out, int out_size, void* d_ws, size_t ws_size,
                              hipStream_t stream) {
  const float* A    = (const float*)d_in[0];
  const float* W    = (const float*)d_in[1];
  const float* bias = (const float*)d_in[2];
  float* out = (float*)d_out;

  const size_t a_elems = (size_t)M_DIM * K_DIM;
  const size_t w_elems = (size_t)N_DIM * K_DIM;
  const size_t need = (a_elems + w_elems) * sizeof(unsigned short);

  if (ws_size < need) {
    naive_linear<<<dim3(N_DIM / 256, M_DIM), 256, 0, stream>>>(A, W, bias, out);
    return;
  }

  unsigned short* Abf = (unsigned short*)d_ws;
  unsigned short* Wbf = Abf + a_elems;
  cvt_f32_bf16<<<2048, 256, 0, stream>>>(A, Abf, (int)(a_elems / 4));
  cvt_f32_bf16<<<2048, 256, 0, stream>>>(W, Wbf, (int)(w_elems / 4));

  gemm256_8ph<<<(M_DIM / 256) * (N_DIM / 256), 512, 0, stream>>>(
      (const __bf16*)Abf, (const __bf16*)Wbf, bias, out);
}

// Round 4
// 274.016 us; speedup vs baseline: 1.6076x; 1.0292x over previous
//
#include <hip/hip_runtime.h>
#include <hip/hip_bf16.h>
#include <cstdint>
#include <cstddef>

#define M_DIM 8192
#define K_DIM 4096
#define N_DIM 4096

typedef __bf16 bf16x8 __attribute__((ext_vector_type(8)));
typedef float  f32x4  __attribute__((ext_vector_type(4)));

__device__ __forceinline__ unsigned short f32_to_bf16_rne(float f) {
  unsigned int u = __builtin_bit_cast(unsigned int, f);
  u += 0x7FFFu + ((u >> 16) & 1u);
  return (unsigned short)(u >> 16);
}

// Single fused fp32->bf16 conversion for both A and W (one launch).
__global__ void __launch_bounds__(256) cvt_both(const float* __restrict__ A,
                                                const float* __restrict__ W,
                                                unsigned short* __restrict__ Abf,
                                                unsigned short* __restrict__ Wbf,
                                                int a4, int tot4) {
  int i = blockIdx.x * blockDim.x + threadIdx.x;
  int stride = gridDim.x * blockDim.x;
  for (; i < tot4; i += stride) {
    const float4* s = (i < a4) ? &reinterpret_cast<const float4*>(A)[i]
                               : &reinterpret_cast<const float4*>(W)[i - a4];
    ushort4* d = (i < a4) ? &reinterpret_cast<ushort4*>(Abf)[i]
                          : &reinterpret_cast<ushort4*>(Wbf)[i - a4];
    float4 v = *s;
    ushort4 o;
    o.x = f32_to_bf16_rne(v.x);
    o.y = f32_to_bf16_rne(v.y);
    o.z = f32_to_bf16_rne(v.z);
    o.w = f32_to_bf16_rne(v.w);
    *d = o;
  }
}

__device__ __forceinline__ void gload16(const void* g, void* l) {
  __builtin_amdgcn_global_load_lds((const __attribute__((address_space(1))) void*)g,
                                   (__attribute__((address_space(3))) void*)l, 16, 0, 0);
}

// 256x256-tile, BK=64, 8-wave (2Mx4N), 8-phase pipelined GEMM.
// ROUND-4 CHANGE vs round 3: single barrier per phase (at END), no explicit
// lgkmcnt(0)/sched_barrier before MFMA. The ds_reads are plain C++ loads, so
// the compiler emits fine-grained counted lgkmcnt between reads and dependent
// MFMAs -> within-wave overlap of LDS drain with MFMA; the removed mid-phase
// barrier lets waves drift within a phase -> cross-wave LDS/MFMA overlap.
// Round-3 counters showed strict alternation: MfmaUtil 51% == predicted
// 620cy MFMA / (620+576cy LDS) serialization.
//
// Safety audit for the relaxed schedule:
//  - Staged-data visibility is gated ONLY by VM(n) asm (with "memory"
//    clobber, so no load hoists across it) + the following barrier:
//    window ph5..ph8 reads only buf1(k+1), landed by VM(4)@ph4;
//    window ph1..ph4 reads only buf0(k+2), landed by VM(4)@ph8. ✓
//  - Stage-write vs ds_read WAR: stage slot region is disjoint from reads in
//    its own phase AND in adjacent phases (checked below per phase), so the
//    schedule tolerates ±1-phase scheduler slip:
//      ph1 stage b1.A0 | ph1 reads buf0.{A0..,B0}, ph8(prev) reads none, ph2
//          reads buf0.B1  -> disjoint ✓
//      ph2 stage b1.A1 | ph1/ph2/ph3 reads: buf0 only ✓
//      ph3 stage b0.B0 | ph2 reads buf0.B1 (other half), ph3 reads buf0.A1,
//          ph4 reads none ✓
//      ph4 stage b0.B1 | ph3 buf0.A1, ph5 buf1 ✓
//      ph5 stage b0.A0 | ph4 none, ph5/ph6 buf1 ✓
//      ph6 stage b0.A1 | buf1 reads only ✓
//      ph7 stage b1.B0 | ph6 reads buf1.B1 (other half), ph7 reads buf1.A1 ✓
//      ph8 stage b1.B1 | ph7 buf1.A1, ph1(next) buf0 ✓
//  - Waves arriving at BAR have completed their reads (data in regs before
//    their MFMAs finish), so stage slots placed >=1 phase after a region's
//    last collective read remain safe. (Collective reads: buf.B fully read
//    after ph1+ph2 / ph5+ph6; buf.A after ph1+ph3 / ph5+ph7.)
//  - vmcnt audit unchanged from round 3 (2 loads/STAGE, in-order):
//    end-ph4: outstanding {prev ph7,8, ph1..4}=12, oldest 8 = buf1(k+1) -> VM(4);
//    end-ph8: outstanding {ph3..8}=12, oldest 8 = buf0(k+2) -> VM(4).
__global__ void __launch_bounds__(512, 2)
gemm256_8ph(const __bf16* __restrict__ A, const __bf16* __restrict__ W,
            const float* __restrict__ bias, float* __restrict__ out) {
  __shared__ __align__(16) char lds[131072];

  const int tid  = threadIdx.x;
  const int wave = tid >> 6, lane = tid & 63;
  const int wm = wave >> 2, wn = wave & 3;   // 2 x 4 wave grid, each owns 128x64
  const int fr = lane & 15, ko = lane >> 4;

  // Bijective XCD swizzle (512 % 8 == 0): XCD x gets 64 consecutive swzids =
  // 2 B-panels (4 MB = its L2).
  const int swzid = ((blockIdx.x & 7) << 6) + (blockIdx.x >> 3);
  const int bm = swzid & 31, bn = swzid >> 5;
  const int brow = bm << 8, bcol = bn << 8;

  // Staging: half-tile = 128 rows x 64 k (16 KiB), 512 threads x 2 gload16.
  // T2 swizzle: LDS 16B-chunk (row, j) holds global k-chunk j ^ (row&7),
  // via pre-swizzled global source + linear (wave-uniform) LDS dest.
  const int r0 = tid >> 3;
  const int jc = (((tid & 7) ^ (r0 & 7)) << 4);
  const char* aSrc = (const char*)A + (size_t)(brow + r0) * (K_DIM * 2) + jc;
  const char* bSrc = (const char*)W + (size_t)(bcol + r0) * (K_DIM * 2) + jc;
  char* dstW = lds + (wave << 10);  // wave-uniform LDS base

#define STAGE(ms, h, bb, kt) do {                                              \
    const char* s_ = ((ms) ? bSrc : aSrc)                                      \
        + (size_t)(h) * (128ull * K_DIM * 2) + (size_t)(kt) * 128;             \
    char* d_ = dstW + (bb) * 65536 + (ms) * 32768 + (h) * 16384;               \
    gload16(s_, d_);                                                           \
    gload16(s_ + 64ull * K_DIM * 2, d_ + 8192);                                \
  } while (0)

  bf16x8 a[4][2];   // current m-half fragments (4 m-frags x 2 k-steps)
  bf16x8 b[4][2];   // 4 n-frags x 2 k-steps
  f32x4 acc[8][4] = {};

#define LDA8(bb, mh) do {                                                      \
    _Pragma("unroll") for (int ml = 0; ml < 4; ++ml)                           \
    _Pragma("unroll") for (int k2 = 0; k2 < 2; ++k2) {                         \
      int ra_ = (wm << 7) + ((mh) << 6) + (ml << 4) + fr;                      \
      int off_ = ((ra_ << 7) + (k2 << 6) + (ko << 4)) ^ ((ra_ & 7) << 4);      \
      a[ml][k2] = *(const bf16x8*)(lds + (bb) * 65536 + off_); }               \
  } while (0)

#define LDB4(bb, nh) do {                                                      \
    _Pragma("unroll") for (int nl = 0; nl < 2; ++nl)                           \
    _Pragma("unroll") for (int k2 = 0; k2 < 2; ++k2) {                         \
      int rb_ = (wn << 6) + ((nh) << 5) + (nl << 4) + fr;                      \
      int off_ = ((rb_ << 7) + (k2 << 6) + (ko << 4)) ^ ((rb_ & 7) << 4);      \
      b[(nh) * 2 + nl][k2] = *(const bf16x8*)(lds + (bb) * 65536 + 32768 + off_); } \
  } while (0)

#define MFMAQ(mh, nh) do {                                                     \
    __builtin_amdgcn_s_setprio(1);                                             \
    _Pragma("unroll") for (int ml = 0; ml < 4; ++ml)                           \
    _Pragma("unroll") for (int nl = 0; nl < 2; ++nl)                           \
    _Pragma("unroll") for (int k2 = 0; k2 < 2; ++k2)                           \
      acc[(mh) * 4 + ml][(nh) * 2 + nl] = __builtin_amdgcn_mfma_f32_16x16x32_bf16( \
          a[ml][k2], b[(nh) * 2 + nl][k2], acc[(mh) * 4 + ml][(nh) * 2 + nl], 0, 0, 0); \
    __builtin_amdgcn_s_setprio(0);                                             \
  } while (0)

#define BAR() __builtin_amdgcn_s_barrier()
#define VM(n) asm volatile("s_waitcnt vmcnt(" #n ")" ::: "memory")

  // Prologue: buf0 <- k0 (all 4 halves), buf1 <- k1 (B0,B1). 12 outstanding;
  // VM(4) -> oldest 8 (= all of buf0 k0) landed.
  STAGE(1, 0, 0, 0);
  STAGE(1, 1, 0, 0);
  STAGE(0, 0, 0, 0);
  STAGE(0, 1, 0, 0);
  STAGE(1, 0, 1, 1);
  STAGE(1, 1, 1, 1);
  VM(4);
  BAR();

  for (int i = 0; i < 31; ++i) {
    const int kb = 2 * i;
    // ph1: Q(0,0) on buf0 | stage b1.A0 <- k+1
    LDA8(0, 0); LDB4(0, 0); STAGE(0, 0, 1, kb + 1);
    MFMAQ(0, 0); BAR();
    // ph2: Q(0,1) | stage b1.A1 <- k+1
    LDB4(0, 1); STAGE(0, 1, 1, kb + 1);
    MFMAQ(0, 1); BAR();
    // ph3: Q(1,1) | stage b0.B0 <- k+2
    LDA8(0, 1); STAGE(1, 0, 0, kb + 2);
    MFMAQ(1, 1); BAR();
    // ph4: Q(1,0) | stage b0.B1 <- k+2 | VM(4): buf1(k+1) landed
    STAGE(1, 1, 0, kb + 2);
    MFMAQ(1, 0); VM(4); BAR();
    // ph5: Q(0,0) on buf1 | stage b0.A0 <- k+2
    LDA8(1, 0); LDB4(1, 0); STAGE(0, 0, 0, kb + 2);
    MFMAQ(0, 0); BAR();
    // ph6: Q(0,1) | stage b0.A1 <- k+2
    LDB4(1, 1); STAGE(0, 1, 0, kb + 2);
    MFMAQ(0, 1); BAR();
    // ph7: Q(1,1) | stage b1.B0 <- k+3
    LDA8(1, 1); STAGE(1, 0, 1, kb + 3);
    MFMAQ(1, 1); BAR();
    // ph8: Q(1,0) | stage b1.B1 <- k+3 | VM(4): buf0(k+2) landed
    STAGE(1, 1, 1, kb + 3);
    MFMAQ(1, 0); VM(4); BAR();
  }

  // Peel: buf0 = k62, buf1 = k63. Stage only b1.A0/A1 <- k63; VM(0) at ph4
  // (8 outstanding, all buf1 k63).
  LDA8(0, 0); LDB4(0, 0); STAGE(0, 0, 1, 63);
  MFMAQ(0, 0); BAR();
  LDB4(0, 1); STAGE(0, 1, 1, 63);
  MFMAQ(0, 1); BAR();
  LDA8(0, 1);
  MFMAQ(1, 1); BAR();
  MFMAQ(1, 0); VM(0); BAR();
  LDA8(1, 0); LDB4(1, 0);
  MFMAQ(0, 0); BAR();
  LDB4(1, 1);
  MFMAQ(0, 1); BAR();
  LDA8(1, 1);
  MFMAQ(1, 1); BAR();
  MFMAQ(1, 0);

  // Epilogue: C/D mapping col=lane&15, row=(lane>>4)*4+j (m89-verified), + bias.
  const int oc0 = bcol + (wn << 6) + fr;
  const int or0 = brow + (wm << 7) + (ko << 2);
  float bv[4];
#pragma unroll
  for (int nl = 0; nl < 4; ++nl) bv[nl] = bias[oc0 + nl * 16];
#pragma unroll
  for (int ml = 0; ml < 8; ++ml)
#pragma unroll
    for (int nl = 0; nl < 4; ++nl)
#pragma unroll
      for (int j = 0; j < 4; ++j)
        out[(size_t)(or0 + ml * 16 + j) * N_DIM + (oc0 + nl * 16)] =
            acc[ml][nl][j] + bv[nl];

#undef STAGE
#undef LDA8
#undef LDB4
#undef MFMAQ
#undef BAR
#undef VM
}

// Safety net if d_ws is too small for bf16 copies of A and W: correct but slow.
__global__ void naive_linear(const float* __restrict__ A, const float* __restrict__ W,
                             const float* __restrict__ bias, float* __restrict__ out) {
  int n = blockIdx.y;
  int o = blockIdx.x * 256 + threadIdx.x;
  const float* a = A + (size_t)n * K_DIM;
  const float* w = W + (size_t)o * K_DIM;
  float acc = 0.f;
  for (int k = 0; k < K_DIM; ++k) acc += a[k] * w[k];
  out[(size_t)n * N_DIM + o] = acc + bias[o];
}

extern "C" void kernel_launch(void* const* d_in, const int* in_sizes, int n_in,
                              void* d_out, int out_size, void* d_ws, size_t ws_size,
                              hipStream_t stream) {
  const float* A    = (const float*)d_in[0];
  const float* W    = (const float*)d_in[1];
  const float* bias = (const float*)d_in[2];
  float* out = (float*)d_out;

  const size_t a_elems = (size_t)M_DIM * K_DIM;
  const size_t w_elems = (size_t)N_DIM * K_DIM;
  const size_t need = (a_elems + w_elems) * sizeof(unsigned short);

  if (ws_size < need) {
    naive_linear<<<dim3(N_DIM / 256, M_DIM), 256, 0, stream>>>(A, W, bias, out);
    return;
  }

  unsigned short* Abf = (unsigned short*)d_ws;
  unsigned short* Wbf = Abf + a_elems;
  const int a4 = (int)(a_elems / 4), tot4 = (int)((a_elems + w_elems) / 4);
  cvt_both<<<2048, 256, 0, stream>>>(A, W, Abf, Wbf, a4, tot4);

  gemm256_8ph<<<(M_DIM / 256) * (N_DIM / 256), 512, 0, stream>>>(
      (const __bf16*)Abf, (const __bf16*)Wbf, bias, out);
}